// Round 1
// baseline (247.079 us; speedup 1.0000x reference)
//
#include <hip/hip_runtime.h>

#define BATCH 131072
#define NS 64
#define NF 128
#define NTOT 192   // NS + NF
#define WAVES_PER_BLOCK 4

__global__ __launch_bounds__(256) void pdf_sampler_kernel(
    const float* __restrict__ near_p,
    const float* __restrict__ far_p,
    const float* __restrict__ density,
    const float* __restrict__ rgb,
    float* __restrict__ out)
{
    const int lane = threadIdx.x & 63;
    const int wave = threadIdx.x >> 6;
    const int ray  = blockIdx.x * WAVES_PER_BLOCK + wave;

    __shared__ float s_cdf [WAVES_PER_BLOCK][NS];
    __shared__ float s_mids[WAVES_PER_BLOCK][NS];
    __shared__ float s_fine[WAVES_PER_BLOCK][NF];
    __shared__ float s_comb[WAVES_PER_BLOCK][NTOT];

    const float nearv = near_p[ray];
    const float farv  = far_p[ray];

    // zs_edges: near*(1-u) + far*u, u = i/64 (exact: 1/64 is a power of two)
    const float u0 = (float)lane       * (1.0f / 64.0f);
    const float u1 = (float)(lane + 1) * (1.0f / 64.0f);
    const float zs = nearv * (1.0f - u0) + farv * u0;
    const float ze = nearv * (1.0f - u1) + farv * u1;
    const float delta = ze - zs;
    const float mid   = 0.5f * (zs + ze);

    const float dens  = density[ray * NS + lane];
    const float alpha = 1.0f - expf(-dens * delta);

    // trans = exclusive prefix product of (1 - alpha): Hillis-Steele shfl scan
    float p = 1.0f - alpha;
    #pragma unroll
    for (int off = 1; off < 64; off <<= 1) {
        float t = __shfl_up(p, off, 64);
        if (lane >= off) p *= t;
    }
    float trans = __shfl_up(p, 1, 64);
    if (lane == 0) trans = 1.0f;
    const float w = alpha * trans;

    // wsum = sum(weight) across wave
    float wsum = w;
    #pragma unroll
    for (int off = 32; off; off >>= 1) wsum += __shfl_xor(wsum, off, 64);

    // cdf = inclusive cumsum of pdf
    float cdfv = w / (wsum + 1e-6f);
    #pragma unroll
    for (int off = 1; off < 64; off <<= 1) {
        float t = __shfl_up(cdfv, off, 64);
        if (lane >= off) cdfv += t;
    }
    s_cdf [wave][lane] = cdfv;
    s_mids[wave][lane] = mid;

    // weighted reductions: rgb (3), depth numerator
    const float r = rgb[(ray * NS + lane) * 3 + 0];
    const float g = rgb[(ray * NS + lane) * 3 + 1];
    const float b = rgb[(ray * NS + lane) * 3 + 2];
    float wr = w * r, wg = w * g, wb = w * b, wm = w * mid;
    #pragma unroll
    for (int off = 32; off; off >>= 1) {
        wr += __shfl_xor(wr, off, 64);
        wg += __shfl_xor(wg, off, 64);
        wb += __shfl_xor(wb, off, 64);
        wm += __shfl_xor(wm, off, 64);
    }
    if (lane == 0) {
        float* rgb_out   = out + (size_t)BATCH * NTOT;
        float* depth_out = rgb_out + (size_t)BATCH * 3;
        float* acc_out   = depth_out + BATCH;
        rgb_out[ray * 3 + 0] = wr;
        rgb_out[ray * 3 + 1] = wg;
        rgb_out[ray * 3 + 2] = wb;
        depth_out[ray] = wm / (wsum + 1e-8f);
        acc_out[ray]   = wsum;
    }

    __syncthreads();

    // 128 fine samples: inverse-CDF (searchsorted side='right'), 2 per lane
    const float* cdf  = s_cdf[wave];
    const float* mids = s_mids[wave];
    #pragma unroll
    for (int k = lane; k < NF; k += 64) {
        const float u = 0.05f + (0.9f / 127.0f) * (float)k;
        int lo = 0, hi = NS;          // upper_bound: first idx with cdf[idx] > u
        while (lo < hi) {
            int m = (lo + hi) >> 1;
            if (cdf[m] <= u) lo = m + 1; else hi = m;
        }
        const int inds  = lo;
        const int below = inds > 0 ? inds - 1 : 0;
        const int above = inds < NS - 1 ? inds : NS - 1;
        const float cb = cdf[below], ca = cdf[above];
        const float bb = mids[below], ba = mids[above];
        float denom = ca - cb;
        if (denom < 1e-5f) denom = 1.0f;
        const float t = (u - cb) / denom;
        s_fine[wave][k] = bb + t * (ba - bb);
    }

    __syncthreads();

    // Merge: both arrays sorted. Stable rank = own idx + rank in other array.
    const float* fine = s_fine[wave];
    {
        // mids tie-break first: pos = i + count(fine < mid)  (lower_bound)
        int lo = 0, hi = NF;
        while (lo < hi) {
            int m = (lo + hi) >> 1;
            if (fine[m] < mid) lo = m + 1; else hi = m;
        }
        s_comb[wave][lane + lo] = mid;
    }
    #pragma unroll
    for (int k = lane; k < NF; k += 64) {
        const float f = fine[k];
        int lo = 0, hi = NS;          // count(mids <= f): upper_bound
        while (lo < hi) {
            int m = (lo + hi) >> 1;
            if (mids[m] <= f) lo = m + 1; else hi = m;
        }
        s_comb[wave][k + lo] = f;
    }

    __syncthreads();

    // Coalesced write of the 192-float combined segment (48 float4 per ray)
    float* comb_out = out + (size_t)ray * NTOT;
    if (lane < 48) {
        const float* src = &s_comb[wave][lane * 4];
        float4 v = make_float4(src[0], src[1], src[2], src[3]);
        reinterpret_cast<float4*>(comb_out)[lane] = v;
    }
}

extern "C" void kernel_launch(void* const* d_in, const int* in_sizes, int n_in,
                              void* d_out, int out_size, void* d_ws, size_t ws_size,
                              hipStream_t stream) {
    const float* near_p  = (const float*)d_in[0];
    const float* far_p   = (const float*)d_in[1];
    const float* density = (const float*)d_in[2];
    const float* rgb     = (const float*)d_in[3];
    float* out = (float*)d_out;

    const int grid = BATCH / WAVES_PER_BLOCK;  // 32768 blocks of 256 threads
    pdf_sampler_kernel<<<grid, 256, 0, stream>>>(near_p, far_p, density, rgb, out);
}

// Round 2
// 235.688 us; speedup vs baseline: 1.0483x; 1.0483x over previous
//
#include <hip/hip_runtime.h>

#define BATCH 131072
#define NS 64
#define NF 128
#define NTOT 192   // NS + NF
#define WPB 4      // waves (rays) per block

__global__ __launch_bounds__(256) void pdf_sampler_kernel(
    const float* __restrict__ near_p,
    const float* __restrict__ far_p,
    const float* __restrict__ density,
    const float* __restrict__ rgb,
    float* __restrict__ out)
{
    const int lane = threadIdx.x & 63;
    const int wave = threadIdx.x >> 6;
    const int ray  = blockIdx.x * WPB + wave;

    __shared__ float2 s_cm  [WPB][NS];    // (cdf, mid) packed for ds_read_b64
    __shared__ int    s_inds[WPB][NF];
    __shared__ __align__(16) float s_comb[WPB][NTOT];

    const float nearv = near_p[ray];
    const float farv  = far_p[ray];

    // zs_edges: near*(1-u) + far*u, u = i/64
    const float u0 = (float)lane       * (1.0f / 64.0f);
    const float u1 = (float)(lane + 1) * (1.0f / 64.0f);
    const float zs = nearv * (1.0f - u0) + farv * u0;
    const float ze = nearv * (1.0f - u1) + farv * u1;
    const float delta = ze - zs;
    const float mid   = 0.5f * (zs + ze);

    const float dens = density[ray * NS + lane];

    // ONE scan: S = inclusive cumsum(density*delta).
    // trans_excl = exp(-S_prev); alpha = 1-exp(-dd); w = e_prev - e  (telescoped)
    float S = dens * delta;
    #pragma unroll
    for (int off = 1; off < 64; off <<= 1) {
        float t = __shfl_up(S, off, 64);
        if (lane >= off) S += t;
    }
    const float e = expf(-S);
    float eprev = __shfl_up(e, 1, 64);
    if (lane == 0) eprev = 1.0f;
    const float w = eprev - e;

    // cumsum(w) telescopes: cdf_j = (1 - e_j) / (wsum + 1e-6), wsum = 1 - e_63
    const float wsum = 1.0f - __shfl(e, 63, 64);
    const float cdfv = (1.0f - e) * __builtin_amdgcn_rcpf(wsum + 1e-6f);

    s_cm[wave][lane] = make_float2(cdfv, mid);

    // t_j = first k in [0,128] with u_k >= cdf_j  (u_k = 0.05 + step*k, uniform grid)
    const float step = 0.9f / 127.0f;
    int t = (int)ceilf((cdfv - 0.05f) * (127.0f / 0.9f));
    t = t < 0 ? 0 : (t > 128 ? 128 : t);
    while (t > 0   && __fmaf_rn(step, (float)(t - 1), 0.05f) >= cdfv) --t;
    while (t < 128 && __fmaf_rn(step, (float)t,       0.05f) <  cdfv) ++t;

    int t1 = __shfl_down(t, 1, 64);
    if (lane == 63) t1 = 128;
    const int t0 = __shfl(t, 0, 64);

    // inds_k = searchsorted_right(cdf, u_k) = #{j: t_j <= k}.
    // k < t_0 -> inds 0 (disjoint region, no ordering hazard with scatter below)
    for (int k = lane; k < t0; k += 64) s_inds[wave][k] = 0;
    // lane j owns k in [t_j, t_{j+1}) -> inds = j+1
    for (int k = t; k < t1; ++k) s_inds[wave][k] = lane + 1;

    // weighted reductions: rgb (3 ch) + depth numerator (wsum is already free)
    const float r = rgb[(ray * NS + lane) * 3 + 0];
    const float g = rgb[(ray * NS + lane) * 3 + 1];
    const float b = rgb[(ray * NS + lane) * 3 + 2];
    float wr = w * r, wg = w * g, wb = w * b, wm = w * mid;
    #pragma unroll
    for (int off = 32; off; off >>= 1) {
        wr += __shfl_xor(wr, off, 64);
        wg += __shfl_xor(wg, off, 64);
        wb += __shfl_xor(wb, off, 64);
        wm += __shfl_xor(wm, off, 64);
    }
    if (lane == 0) {
        float* rgb_out   = out + (size_t)BATCH * NTOT;
        float* depth_out = rgb_out + (size_t)BATCH * 3;
        float* acc_out   = depth_out + BATCH;
        rgb_out[ray * 3 + 0] = wr;
        rgb_out[ray * 3 + 1] = wg;
        rgb_out[ray * 3 + 2] = wb;
        depth_out[ray] = wm / (wsum + 1e-8f);
        acc_out[ray]   = wsum;
    }

    __syncthreads();

    // Fine samples: inds from LDS; interp; merge rank is closed-form:
    //   fine_k in [mids[below], mids[above]] => rank among mids = below+1
    //   => combined position = k + below + 1  (consistent permutation w/ pos_mid)
    #pragma unroll
    for (int i = 0; i < 2; ++i) {
        const int k = lane + 64 * i;
        const int inds  = s_inds[wave][k];
        const int below = inds > 0 ? inds - 1 : 0;
        const int above = inds < 63 ? inds : 63;
        const float2 cb2 = s_cm[wave][below];
        const float2 ca2 = s_cm[wave][above];
        float denom = ca2.x - cb2.x;
        if (denom < 1e-5f) denom = 1.0f;
        const float u  = __fmaf_rn(step, (float)k, 0.05f);
        const float tt = (u - cb2.x) * __builtin_amdgcn_rcpf(denom);
        const float fine = cb2.y + tt * (ca2.y - cb2.y);
        s_comb[wave][k + below + 1] = fine;
    }
    // mid_j position: j + #{k: rank_k <= j} = j + t_j (j>=1), 0 for j==0
    const int pm = (lane == 0) ? 0 : lane + t;
    s_comb[wave][pm] = mid;

    __syncthreads();

    // Coalesced write of the 192-float combined segment (48 float4 per ray)
    float* comb_out = out + (size_t)ray * NTOT;
    if (lane < 48) {
        const float4 v = *reinterpret_cast<const float4*>(&s_comb[wave][lane * 4]);
        reinterpret_cast<float4*>(comb_out)[lane] = v;
    }
}

extern "C" void kernel_launch(void* const* d_in, const int* in_sizes, int n_in,
                              void* d_out, int out_size, void* d_ws, size_t ws_size,
                              hipStream_t stream) {
    const float* near_p  = (const float*)d_in[0];
    const float* far_p   = (const float*)d_in[1];
    const float* density = (const float*)d_in[2];
    const float* rgb     = (const float*)d_in[3];
    float* out = (float*)d_out;

    const int grid = BATCH / WPB;  // 32768 blocks of 256 threads
    pdf_sampler_kernel<<<grid, 256, 0, stream>>>(near_p, far_p, density, rgb, out);
}

// Round 3
// 205.236 us; speedup vs baseline: 1.2039x; 1.1484x over previous
//
#include <hip/hip_runtime.h>

#define BATCH 131072
#define NS 64
#define NF 128
#define NTOT 192   // NS + NF
#define WPB 4      // waves (rays) per block

// wave64 inclusive add-scan via DPP: row_shr 1/2/4/8 (per-16 rows) then
// row_bcast:15 (rows 1,3) and row_bcast:31 (rows 2,3). Lane i = sum lanes 0..i;
// lane 63 = wave total. bound_ctrl=true => invalid source lanes contribute 0.
#define DPP_ADD_F(x, ctrl, rm)                                               \
    x += __int_as_float(__builtin_amdgcn_update_dpp(                         \
        0, __float_as_int(x), ctrl, rm, 0xf, true))
#define DPP_ADD_I(x, ctrl, rm)                                               \
    x += __builtin_amdgcn_update_dpp(0, x, ctrl, rm, 0xf, true)

__device__ __forceinline__ float wave_iscan_f(float x) {
    DPP_ADD_F(x, 0x111, 0xf);   // row_shr:1
    DPP_ADD_F(x, 0x112, 0xf);   // row_shr:2
    DPP_ADD_F(x, 0x114, 0xf);   // row_shr:4
    DPP_ADD_F(x, 0x118, 0xf);   // row_shr:8
    DPP_ADD_F(x, 0x142, 0xa);   // row_bcast:15 -> rows 1,3
    DPP_ADD_F(x, 0x143, 0xc);   // row_bcast:31 -> rows 2,3
    return x;
}
__device__ __forceinline__ int wave_iscan_i(int x) {
    DPP_ADD_I(x, 0x111, 0xf);
    DPP_ADD_I(x, 0x112, 0xf);
    DPP_ADD_I(x, 0x114, 0xf);
    DPP_ADD_I(x, 0x118, 0xf);
    DPP_ADD_I(x, 0x142, 0xa);
    DPP_ADD_I(x, 0x143, 0xc);
    return x;
}

__global__ __launch_bounds__(256) void pdf_sampler_kernel(
    const float* __restrict__ near_p,
    const float* __restrict__ far_p,
    const float* __restrict__ density,
    const float* __restrict__ rgb,
    float* __restrict__ out)
{
    const int lane = threadIdx.x & 63;
    const int wave = threadIdx.x >> 6;
    const int ray  = blockIdx.x * WPB + wave;

    __shared__ float2 s_cm[WPB][NS];          // (cdf, mid)
    __shared__ int2   s_hist2[WPB][NF / 2];   // histogram of t_j over k
    __shared__ __align__(16) float s_comb[WPB][NTOT];

    // All LDS traffic below is wave-local: DS ops from one wave execute in
    // order, so no __syncthreads needed — wave_barrier() fences the compiler.
    const float nearv = near_p[ray];
    const float farv  = far_p[ray];
    const float dens  = density[ray * NS + lane];
    const float r = rgb[(ray * NS + lane) * 3 + 0];
    const float g = rgb[(ray * NS + lane) * 3 + 1];
    const float b = rgb[(ray * NS + lane) * 3 + 2];

    // zs_edges: near*(1-u) + far*u, u = i/64
    const float u0 = (float)lane       * (1.0f / 64.0f);
    const float u1 = (float)(lane + 1) * (1.0f / 64.0f);
    const float zs = nearv * (1.0f - u0) + farv * u0;
    const float ze = nearv * (1.0f - u1) + farv * u1;
    const float delta = ze - zs;
    const float mid   = 0.5f * (zs + ze);

    // Telescoped transmittance: one scan of density*delta does everything.
    const float S = wave_iscan_f(dens * delta);
    const float e = __expf(-S);
    // eprev = wave_shr:1, lane0 keeps old = 1.0f
    const float eprev = __int_as_float(__builtin_amdgcn_update_dpp(
        0x3f800000, __float_as_int(e), 0x138, 0xf, 0xf, false));
    const float w    = eprev - e;
    const float wsum = 1.0f - __shfl(e, 63, 64);
    const float cdfv = (1.0f - e) * __builtin_amdgcn_rcpf(wsum + 1e-6f);

    s_cm[wave][lane] = make_float2(cdfv, mid);
    s_hist2[wave][lane] = make_int2(0, 0);    // zero hist (k=2*lane, 2*lane+1)

    // t_j = first k in [0,128] with u_k >= cdf_j  (u_k = 0.05 + step*k)
    const float step = 0.9f / 127.0f;
    int t = (int)ceilf((cdfv - 0.05f) * (127.0f / 0.9f));
    t = t < 0 ? 0 : (t > 128 ? 128 : t);
    while (t > 0   && __fmaf_rn(step, (float)(t - 1), 0.05f) >= cdfv) --t;
    while (t < 128 && __fmaf_rn(step, (float)t,       0.05f) <  cdfv) ++t;

    __builtin_amdgcn_wave_barrier();
    if (t < 128) atomicAdd(&((int*)s_hist2[wave])[t], 1);  // one balanced op
    __builtin_amdgcn_wave_barrier();

    // inds_k = #{j: t_j <= k} = cumsum(hist)[k]; lane l owns k = 2l, 2l+1
    const int2 h   = s_hist2[wave][lane];
    const int incl = wave_iscan_i(h.x + h.y);
    const int inds0 = incl - h.y;
    const int inds1 = incl;

    // weighted reductions (DPP scan; total lands in lane 63)
    const float wrS = wave_iscan_f(w * r);
    const float wgS = wave_iscan_f(w * g);
    const float wbS = wave_iscan_f(w * b);
    const float wmS = wave_iscan_f(w * mid);
    if (lane == 63) {
        float* rgb_out   = out + (size_t)BATCH * NTOT;
        float* depth_out = rgb_out + (size_t)BATCH * 3;
        float* acc_out   = depth_out + BATCH;
        rgb_out[ray * 3 + 0] = wrS;
        rgb_out[ray * 3 + 1] = wgS;
        rgb_out[ray * 3 + 2] = wbS;
        depth_out[ray] = wmS * __builtin_amdgcn_rcpf(wsum + 1e-8f);
        acc_out[ray]   = wsum;
    }

    // Fine samples + closed-form merge position (k + below + 1)
    #pragma unroll
    for (int i = 0; i < 2; ++i) {
        const int k    = 2 * lane + i;
        const int inds = i ? inds1 : inds0;
        const int below = inds > 0 ? inds - 1 : 0;
        const int above = inds < NS - 1 ? inds : NS - 1;
        const float2 cb2 = s_cm[wave][below];
        const float2 ca2 = s_cm[wave][above];
        float denom = ca2.x - cb2.x;
        if (denom < 1e-5f) denom = 1.0f;
        const float u  = __fmaf_rn(step, (float)k, 0.05f);
        const float tt = (u - cb2.x) * __builtin_amdgcn_rcpf(denom);
        const float fine = __fmaf_rn(tt, ca2.y - cb2.y, cb2.y);
        s_comb[wave][k + below + 1] = fine;
    }
    // mid_j position: j + t_j (j>=1), 0 for j==0
    const int pm = lane ? lane + t : 0;
    s_comb[wave][pm] = mid;

    __builtin_amdgcn_wave_barrier();

    // Coalesced write of the 192-float combined segment (48 float4 per ray)
    float* comb_out = out + (size_t)ray * NTOT;
    if (lane < 48) {
        const float4 v = *reinterpret_cast<const float4*>(&s_comb[wave][lane * 4]);
        reinterpret_cast<float4*>(comb_out)[lane] = v;
    }
}

extern "C" void kernel_launch(void* const* d_in, const int* in_sizes, int n_in,
                              void* d_out, int out_size, void* d_ws, size_t ws_size,
                              hipStream_t stream) {
    const float* near_p  = (const float*)d_in[0];
    const float* far_p   = (const float*)d_in[1];
    const float* density = (const float*)d_in[2];
    const float* rgb     = (const float*)d_in[3];
    float* out = (float*)d_out;

    const int grid = BATCH / WPB;  // 32768 blocks of 256 threads
    pdf_sampler_kernel<<<grid, 256, 0, stream>>>(near_p, far_p, density, rgb, out);
}